// Round 9
// baseline (324.539 us; speedup 1.0000x reference)
//
#include <hip/hip_runtime.h>

typedef __bf16 bf16x8 __attribute__((ext_vector_type(8)));
typedef __bf16 bf16x4 __attribute__((ext_vector_type(4)));
typedef float  f32x4  __attribute__((ext_vector_type(4)));

#define B_ 4
#define T_ 2048
#define H_ 8
#define D_ 64
#define E_ 512

// q scale: D^-0.5 * log2(e)  (softmax computed in exp2 domain)
#define QSCALE 0.18033688011112042f

// async global->LDS, 16B per lane. LDS dest is wave-uniform base + lane*16.
__device__ __forceinline__ void async_ld16(const __bf16* g, __bf16* lds) {
  __builtin_amdgcn_global_load_lds((const __attribute__((address_space(1))) void*)g,
                                   (__attribute__((address_space(3))) void*)lds,
                                   16, 0, 0);
}

// grid barrier: distinct counter per use (zeroed by host memset each launch).
// Release: __threadfence (agent-scope wb) then device-scope add. Acquire:
// agent-scope load + trailing fence (cache inv) before next phase's reads.
__device__ __forceinline__ void gbar(unsigned* c, int nb) {
  __syncthreads();
  __threadfence();
  if (threadIdx.x == 0) {
    __hip_atomic_fetch_add(c, 1u, __ATOMIC_RELEASE, __HIP_MEMORY_SCOPE_AGENT);
    while (__hip_atomic_load(c, __ATOMIC_ACQUIRE, __HIP_MEMORY_SCOPE_AGENT) < (unsigned)nb)
      __builtin_amdgcn_s_sleep(8);
  }
  __syncthreads();
  __threadfence();
}

// ---------------- phase 0: convert x, W_qkv (row-permuted), W_0 ----------------
__device__ void cvt_phase(const float* __restrict__ x, const float* __restrict__ wq,
                          const float* __restrict__ w0, __bf16* __restrict__ xb,
                          __bf16* __restrict__ wqb, __bf16* __restrict__ w0b,
                          int bid, int tid, int nb) {
  // 5242880 elements = 655360 x vec8, grid-strided
  for (long vv = (long)bid * 256 + tid; vv < 655360L; vv += (long)nb * 256) {
    long i = vv * 8;
    const float* src; __bf16* dst; long roff, woff;
    if (i < 4194304L)      { src = x;  dst = xb;  roff = i; woff = i; }
    else if (i < 4980736L) {
      src = wq; dst = wqb; roff = i - 4194304L;
      // src row r = h*192 + d*3 + which -> dst row = which*512 + h*64 + d
      const int r = (int)(roff >> 9), c = (int)(roff & 511);
      const int h = r / 192, rem = r - h * 192;
      const int d = rem / 3, which = rem - d * 3;
      woff = (long)(which * 512 + h * 64 + d) * 512 + c;
    }
    else                   { src = w0; dst = w0b; roff = i - 4980736L; woff = roff; }
    float4 a = *(const float4*)(src + roff);
    float4 b = *(const float4*)(src + roff + 4);
    bf16x8 o;
    o[0] = (__bf16)a.x; o[1] = (__bf16)a.y; o[2] = (__bf16)a.z; o[3] = (__bf16)a.w;
    o[4] = (__bf16)b.x; o[5] = (__bf16)b.y; o[6] = (__bf16)b.z; o[7] = (__bf16)b.w;
    *(bf16x8*)(dst + woff) = o;
  }
}

// ---------------- gemm tile: C = A(MxK) * B(NxK)^T, K=512, TMx128 ----------------
// Double-buffered staging, one barrier per K-step. 4 waves, 16x16x32 bf16 MFMA.
// MODE 0 (TM=128): qkv epilogue (W pre-permuted -> which = n0>>9 block-uniform).
// MODE 1: plain fp32 store, row-major MxN.
template<int MODE, int N, int TM>
__device__ void gemm_tile(char* smem, const __bf16* __restrict__ A,
                          const __bf16* __restrict__ Bm,
                          __bf16* __restrict__ o0, __bf16* __restrict__ o1,
                          __bf16* __restrict__ o2, float* __restrict__ of,
                          int m0, int n0, int tid) {
  constexpr int K = 512;
  constexpr int MI = TM / 32;
  __bf16* AsB = (__bf16*)smem;                 // [2][TM*64]
  __bf16* BsB = (__bf16*)(smem + TM * 256);    // [2][128*64]
  const int wave = tid >> 6, lane = tid & 63;
  const int l15 = lane & 15, l16 = lane >> 4;
  const int waveM = wave >> 1, waveN = wave & 1;
  const int srow = lane >> 3;
  const int sch  = (lane & 7) ^ srow;

  f32x4 acc[MI][4] = {};

  const __bf16* ag = A  + (size_t)(m0 + wave * 8 + srow) * K + sch * 8;
  const __bf16* bg = Bm + (size_t)(n0 + wave * 8 + srow) * K + sch * 8;

  auto stage = [&](int buf, int k0) {
    __bf16* As = AsB + buf * (TM * 64);
    __bf16* Bs = BsB + buf * (128 * 64);
#pragma unroll
    for (int it = 0; it < TM / 32; ++it)
      async_ld16(ag + (size_t)it * 32 * K + k0, &As[(it * 32 + wave * 8) * 64]);
#pragma unroll
    for (int it = 0; it < 4; ++it)
      async_ld16(bg + (size_t)it * 32 * K + k0, &Bs[(it * 32 + wave * 8) * 64]);
  };

  stage(0, 0);
#pragma unroll 2
  for (int kt = 0; kt < 8; ++kt) {
    __builtin_amdgcn_s_waitcnt(0);
    __syncthreads();
    if (kt < 7) stage((kt + 1) & 1, (kt + 1) * 64);
    const __bf16* Ac = AsB + (kt & 1) * (TM * 64);
    const __bf16* Bc = BsB + (kt & 1) * (128 * 64);
#pragma unroll
    for (int ks = 0; ks < 2; ++ks) {
      bf16x8 af[MI], bf[4];
      const int cb = ks * 4 + l16;
#pragma unroll
      for (int i = 0; i < MI; ++i) {
        const int rA = waveM * (TM / 2) + i * 16 + l15;
        af[i] = *(const bf16x8*)&Ac[rA * 64 + ((cb ^ (rA & 7)) * 8)];
      }
#pragma unroll
      for (int i = 0; i < 4; ++i) {
        const int rB = waveN * 64 + i * 16 + l15;
        bf[i] = *(const bf16x8*)&Bc[rB * 64 + ((cb ^ (rB & 7)) * 8)];
      }
#pragma unroll
      for (int mi = 0; mi < MI; ++mi)
#pragma unroll
        for (int ni = 0; ni < 4; ++ni)
          acc[mi][ni] = __builtin_amdgcn_mfma_f32_16x16x32_bf16(af[mi], bf[ni], acc[mi][ni], 0, 0, 0);
    }
  }
  __syncthreads();   // all LDS reads done before epilogue / next tile's staging

  if constexpr (MODE == 0) {
    const int which = n0 >> 9;          // block-uniform after W permutation
    const int b = m0 >> 11;
#pragma unroll
    for (int mi = 0; mi < MI; ++mi) {
#pragma unroll
      for (int ni = 0; ni < 4; ++ni) {
        const int n = n0 + waveN * 64 + ni * 16 + l15;
        const int d = n & 63, h = (n >> 6) & 7;
        const int t = (m0 & (T_ - 1)) + waveM * (TM / 2) + mi * 16 + l16 * 4;
        const size_t bh = (size_t)(b * H_ + h);
        if (which == 0) {
          bf16x4 pv;
#pragma unroll
          for (int r = 0; r < 4; ++r) pv[r] = (__bf16)(acc[mi][ni][r] * QSCALE);
          *(bf16x4*)&o0[(bh * D_ + d) * T_ + t] = pv;            // q [B,H,D,T]
        } else if (which == 1) {
#pragma unroll
          for (int r = 0; r < 4; ++r)
            o1[(bh * T_ + t + r) * D_ + d] = (__bf16)acc[mi][ni][r];  // k [B,H,T,D]
        } else {
          bf16x4 pv;
#pragma unroll
          for (int r = 0; r < 4; ++r) pv[r] = (__bf16)acc[mi][ni][r];
          *(bf16x4*)&o2[(bh * D_ + d) * T_ + t] = pv;            // v [B,H,D,T]
        }
      }
    }
  } else {
#pragma unroll
    for (int mi = 0; mi < MI; ++mi)
#pragma unroll
      for (int ni = 0; ni < 4; ++ni)
#pragma unroll
        for (int r = 0; r < 4; ++r) {
          const int m = m0 + waveM * (TM / 2) + mi * 16 + l16 * 4 + r;
          const int n = n0 + waveN * 64 + ni * 16 + l15;
          of[(size_t)m * N + n] = acc[mi][ni][r];
        }
  }
}

// ---------------- phase 2: flash attention (R5 structure, q-tile 128) ----------------
// Max-free exp2-domain. Tk=64 double-buffered K/V staging, one barrier per kt.
// Waves 2x2 over (t-half 32, q-half 64); Ps wave-private.
__device__ void attn_tile(char* smem, const __bf16* __restrict__ Q,
                          const __bf16* __restrict__ Kk, const __bf16* __restrict__ Vt,
                          __bf16* __restrict__ Out, int bh, int t0q, int tid) {
  // Ks[2]: 0, 8192 ([64 t][64 d] swizzled). Vts[2]: 16384, 24576 ([64 d][64 t]).
  // Ps: 32768, per-wave [64 q][40] bf16 (5120 B each).
  float* Osh = (float*)smem;               // overlay: [2 q2][64 d][68] f32
  float* Lsh = (float*)(smem + 34816);     // overlay: [2 q2][64 q'] f32

  const int wave = tid >> 6, lane = tid & 63;
  const int l15 = lane & 15, l16 = lane >> 4;
  const int tw = wave >> 1, q2 = wave & 1;
  const __bf16* qptr = Q  + (size_t)bh * D_ * T_;   // [D][T], pre-scaled
  const __bf16* kptr = Kk + (size_t)bh * T_ * D_;   // [T][D]
  const __bf16* vptr = Vt + (size_t)bh * D_ * T_;   // [D][T]

  __bf16* Pw = (__bf16*)(smem + 32768) + wave * 2560;   // [64 q][40]

  // Q fragments (wave's 64 q-cols), from [d][t]: one-time scalar loads.
  bf16x8 qf[4][2];
#pragma unroll
  for (int ni = 0; ni < 4; ++ni)
#pragma unroll
    for (int ks = 0; ks < 2; ++ks)
#pragma unroll
      for (int j = 0; j < 8; ++j)
        qf[ni][ks][j] = qptr[(size_t)(ks * 32 + l16 * 8 + j) * T_ +
                             t0q + q2 * 64 + ni * 16 + l15];

  bf16x8 ones;
#pragma unroll
  for (int j = 0; j < 8; ++j) ones[j] = (__bf16)1.0f;

  f32x4 oacc[4][4] = {};
  f32x4 lacc[4] = {};

  const int srow = lane >> 3;
  const int sch  = (lane & 7) ^ srow;

  auto stage = [&](int buf, int t0k) {
    __bf16* Kd = (__bf16*)(smem + buf * 8192);
    __bf16* Vd = (__bf16*)(smem + 16384 + buf * 8192);
#pragma unroll
    for (int i = 0; i < 2; ++i) {
      const int row = i * 32 + wave * 8;
      async_ld16(kptr + (size_t)(t0k + row + srow) * D_ + sch * 8, Kd + row * 64);
      async_ld16(vptr + (size_t)(row + srow) * T_ + t0k + sch * 8, Vd + row * 64);
    }
  };

  stage(0, 0);
#pragma unroll 2
  for (int kt = 0; kt < 32; ++kt) {
    __builtin_amdgcn_s_waitcnt(0);
    __syncthreads();
    if (kt < 31) stage((kt + 1) & 1, (kt + 1) * 64);
    const __bf16* Ksc = (const __bf16*)(smem + (kt & 1) * 8192);
    const __bf16* Vtc = (const __bf16*)(smem + 16384 + (kt & 1) * 8192);

    // S^T[t'][q'] over wave's 32 t x 64 q (log2 domain via QSCALE)
    f32x4 sacc[2][4] = {};
#pragma unroll
    for (int ks = 0; ks < 2; ++ks) {
      bf16x8 kf[2];
      const int cb = ks * 4 + l16;
#pragma unroll
      for (int mi = 0; mi < 2; ++mi) {
        const int rt = tw * 32 + mi * 16 + l15;
        kf[mi] = *(const bf16x8*)&Ksc[rt * 64 + ((cb ^ (rt & 7)) * 8)];
      }
#pragma unroll
      for (int mi = 0; mi < 2; ++mi)
#pragma unroll
        for (int ni = 0; ni < 4; ++ni)
          sacc[mi][ni] = __builtin_amdgcn_mfma_f32_16x16x32_bf16(kf[mi], qf[ni][ks], sacc[mi][ni], 0, 0, 0);
    }

    // P = exp2(S) -> wave-private Ps [q'][t' stride 40]
#pragma unroll
    for (int ni = 0; ni < 4; ++ni)
#pragma unroll
      for (int mi = 0; mi < 2; ++mi) {
        bf16x4 pv;
#pragma unroll
        for (int r = 0; r < 4; ++r) pv[r] = (__bf16)__builtin_amdgcn_exp2f(sacc[mi][ni][r]);
        *(bf16x4*)&Pw[(ni * 16 + l15) * 40 + mi * 16 + l16 * 4] = pv;
      }

    // O += P*V over wave's 32 t ; l += P*1
    {
      bf16x8 pf[4], vf[4];
#pragma unroll
      for (int mq = 0; mq < 4; ++mq)
        pf[mq] = *(const bf16x8*)&Pw[(mq * 16 + l15) * 40 + l16 * 8];
#pragma unroll
      for (int nd = 0; nd < 4; ++nd) {
        const int rd = nd * 16 + l15;
        const int ct = tw * 4 + l16;
        vf[nd] = *(const bf16x8*)&Vtc[rd * 64 + ((ct ^ (rd & 7)) * 8)];
      }
#pragma unroll
      for (int mq = 0; mq < 4; ++mq) {
#pragma unroll
        for (int nd = 0; nd < 4; ++nd)
          oacc[mq][nd] = __builtin_amdgcn_mfma_f32_16x16x32_bf16(pf[mq], vf[nd], oacc[mq][nd], 0, 0, 0);
        lacc[mq] = __builtin_amdgcn_mfma_f32_16x16x32_bf16(pf[mq], ones, lacc[mq], 0, 0, 0);
      }
    }
  }

  // reduce O,l across t-halves; epilogue O/l -> [B,T,H*D] bf16
  __syncthreads();
  if (tw == 1) {
    float* Ow = Osh + q2 * 4352;            // [64 d][68] f32
#pragma unroll
    for (int mq = 0; mq < 4; ++mq)
#pragma unroll
      for (int nd = 0; nd < 4; ++nd)
        *(f32x4*)&Ow[(nd * 16 + l15) * 68 + mq * 16 + l16 * 4] = oacc[mq][nd];
    if (l15 == 0)
#pragma unroll
      for (int mq = 0; mq < 4; ++mq)
        *(f32x4*)&Lsh[q2 * 64 + mq * 16 + l16 * 4] = lacc[mq];
  }
  __syncthreads();
  if (tw == 0) {
    const int b = bh >> 3, hcol = (bh & 7) * D_;
    float* Ow = Osh + q2 * 4352;
#pragma unroll
    for (int mq = 0; mq < 4; ++mq) {
      const f32x4 lv = *(const f32x4*)&Lsh[q2 * 64 + mq * 16 + l16 * 4];
      f32x4 linv;
#pragma unroll
      for (int r = 0; r < 4; ++r) linv[r] = __builtin_amdgcn_rcpf(lacc[mq][r] + lv[r]);
#pragma unroll
      for (int nd = 0; nd < 4; ++nd) {
        const f32x4 op = *(const f32x4*)&Ow[(nd * 16 + l15) * 68 + mq * 16 + l16 * 4];
#pragma unroll
        for (int r = 0; r < 4; ++r) {
          const int trow = t0q + q2 * 64 + mq * 16 + l16 * 4 + r;
          Out[((size_t)b * T_ + trow) * E_ + hcol + nd * 16 + l15] =
              (__bf16)((oacc[mq][nd][r] + op[r]) * linv[r]);
        }
      }
    }
  }
  __syncthreads();
}

// ---------------- fused persistent kernel (plain launch + manual grid barrier) ----------------
__global__ __launch_bounds__(256, 2)
void mha_fused(const float* x, const float* Wqkv, const float* W0,
               __bf16* xb, __bf16* wqb, __bf16* w0b,
               __bf16* q, __bf16* k, __bf16* v, __bf16* ao, float* out,
               unsigned* bar, int nb) {
  __shared__ __align__(16) char smem[65536];
  const int bid = blockIdx.x, tid = threadIdx.x;

  // phase 0: dtype conversion + W permutation
  cvt_phase(x, Wqkv, W0, xb, wqb, w0b, bid, tid, nb);
  gbar(bar + 0, nb);

  // phase 1: QKV projection, 768 tiles grid-strided
  for (int tile = bid; tile < 768; tile += nb)
    gemm_tile<0, 3 * H_ * D_, 128>(smem, xb, wqb, q, k, v, nullptr,
                                   (tile / 12) * 128, (tile % 12) * 128, tid);
  gbar(bar + 16, nb);

  // phase 2: attention, 512 tiles (32 bh x 16 q-tiles)
  for (int tile = bid; tile < 512; tile += nb)
    attn_tile(smem, q, k, v, ao, tile >> 4, (tile & 15) * 128, tid);
  gbar(bar + 32, nb);

  // phase 3: output projection, 512 tiles (TM=64)
  for (int tile = bid; tile < 512; tile += nb)
    gemm_tile<1, E_, 64>(smem, ao, w0b, nullptr, nullptr, nullptr, out,
                         (tile >> 2) * 64, (tile & 3) * 128, tid);
}

extern "C" void kernel_launch(void* const* d_in, const int* in_sizes, int n_in,
                              void* d_out, int out_size, void* d_ws, size_t ws_size,
                              hipStream_t stream) {
  const float* x    = (const float*)d_in[0];
  const float* Wqkv = (const float*)d_in[1];
  const float* W0   = (const float*)d_in[2];
  float* out = (float*)d_out;

  char* ws = (char*)d_ws;
  __bf16* xb  = (__bf16*)ws;                                    // 8192*512 bf16
  __bf16* wqb = (__bf16*)(ws + 8388608);                        // 1536*512 (permuted)
  __bf16* w0b = (__bf16*)(ws + 8388608 + 1572864);              // 512*512
  __bf16* q   = (__bf16*)(ws + 8388608 + 1572864 + 524288);     // [B,H,D,T]
  __bf16* k   = q + 4194304;                                    // [B,H,T,D]
  __bf16* v   = k + 4194304;                                    // [B,H,D,T]
  __bf16* ao  = xb;  // reuse: xb consumed by QKV GEMM before attn writes ao
  unsigned* bar = (unsigned*)(ws + 35651584);                   // 3 counters, 64B apart

  // adaptive grid: guarantee co-residency by construction (query, not assume)
  int occ = 0, dev = 0, cus = 0;
  hipGetDevice(&dev);
  hipOccupancyMaxActiveBlocksPerMultiprocessor(&occ, (const void*)mha_fused, 256, 0);
  hipDeviceGetAttribute(&cus, hipDeviceAttributeMultiprocessorCount, dev);
  if (occ < 1) occ = 1;
  if (cus < 1) cus = 256;
  int nb = occ * cus;
  if (nb > 512) nb = 512;

  hipMemsetAsync(bar, 0, 256, stream);
  mha_fused<<<nb, 256, 0, stream>>>(x, Wqkv, W0, xb, wqb, w0b, q, k, v, ao, out, bar, nb);
}

// Round 10
// 152.276 us; speedup vs baseline: 2.1313x; 2.1313x over previous
//
#include <hip/hip_runtime.h>

typedef __bf16 bf16x8 __attribute__((ext_vector_type(8)));
typedef __bf16 bf16x4 __attribute__((ext_vector_type(4)));
typedef float  f32x4  __attribute__((ext_vector_type(4)));

#define B_ 4
#define T_ 2048
#define H_ 8
#define D_ 64
#define E_ 512

// q scale: D^-0.5 * log2(e)  (softmax computed in exp2 domain)
#define QSCALE 0.18033688011112042f

// async global->LDS, 16B per lane. LDS dest is wave-uniform base + lane*16.
__device__ __forceinline__ void async_ld16(const __bf16* g, __bf16* lds) {
  __builtin_amdgcn_global_load_lds((const __attribute__((address_space(1))) void*)g,
                                   (__attribute__((address_space(3))) void*)lds,
                                   16, 0, 0);
}

// converts x, W_qkv (row-permuted to [which][h][d] order), W_0
__global__ void cvt_all(const float* __restrict__ x, const float* __restrict__ wq,
                        const float* __restrict__ w0, __bf16* __restrict__ xb,
                        __bf16* __restrict__ wqb, __bf16* __restrict__ w0b) {
  long i = (long)(blockIdx.x * 256 + threadIdx.x) * 8;
  const float* src; __bf16* dst; long roff, woff;
  if (i < 4194304L)      { src = x;  dst = xb;  roff = i; woff = i; }
  else if (i < 4980736L) {
    src = wq; dst = wqb; roff = i - 4194304L;
    // src row r = h*192 + d*3 + which  ->  dst row = which*512 + h*64 + d
    const int r = (int)(roff >> 9), c = (int)(roff & 511);
    const int h = r / 192, rem = r - h * 192;
    const int d = rem / 3, which = rem - d * 3;
    woff = (long)(which * 512 + h * 64 + d) * 512 + c;
  }
  else                   { src = w0; dst = w0b; roff = i - 4980736L; woff = roff; }
  float4 a = *(const float4*)(src + roff);
  float4 b = *(const float4*)(src + roff + 4);
  bf16x8 o;
  o[0] = (__bf16)a.x; o[1] = (__bf16)a.y; o[2] = (__bf16)a.z; o[3] = (__bf16)a.w;
  o[4] = (__bf16)b.x; o[5] = (__bf16)b.y; o[6] = (__bf16)b.z; o[7] = (__bf16)b.w;
  *(bf16x8*)(dst + woff) = o;
}

// C = A(MxK) * B(NxK)^T, K=512, TMx128 tile, 4 waves, 16x16x32 bf16 MFMA.
// Double-buffered staging, one barrier per K-step.
// MODE 0 (TM=128): qkv epilogue (W pre-permuted -> which = n0>>9 block-uniform).
// MODE 1: plain fp32 store, row-major MxN.
template<int MODE, int N, int TM>
__global__ __launch_bounds__(256, 2)
void gemm_bt(const __bf16* __restrict__ A, const __bf16* __restrict__ Bm,
             __bf16* __restrict__ o0, __bf16* __restrict__ o1, __bf16* __restrict__ o2,
             float* __restrict__ of) {
  constexpr int K = 512;
  constexpr int MI = TM / 32;                 // acc tiles in m per wave
  __shared__ __bf16 As[2][TM * 64];
  __shared__ __bf16 Bs[2][128 * 64];
  const int tid  = threadIdx.x;
  const int wave = tid >> 6, lane = tid & 63;
  const int l15 = lane & 15, l16 = lane >> 4;
  const int m0 = blockIdx.y * TM, n0 = blockIdx.x * 128;
  const int waveM = wave >> 1, waveN = wave & 1;
  const int srow = lane >> 3;
  const int sch  = (lane & 7) ^ srow;

  f32x4 acc[MI][4] = {};

  const __bf16* ag = A  + (size_t)(m0 + wave * 8 + srow) * K + sch * 8;
  const __bf16* bg = Bm + (size_t)(n0 + wave * 8 + srow) * K + sch * 8;

  auto stage = [&](int buf, int k0) {
#pragma unroll
    for (int it = 0; it < TM / 32; ++it)
      async_ld16(ag + (size_t)it * 32 * K + k0, &As[buf][(it * 32 + wave * 8) * 64]);
#pragma unroll
    for (int it = 0; it < 4; ++it)
      async_ld16(bg + (size_t)it * 32 * K + k0, &Bs[buf][(it * 32 + wave * 8) * 64]);
  };

  stage(0, 0);
#pragma unroll 2
  for (int kt = 0; kt < 8; ++kt) {
    __builtin_amdgcn_s_waitcnt(0);
    __syncthreads();
    if (kt < 7) stage((kt + 1) & 1, (kt + 1) * 64);
    const __bf16* Ac = As[kt & 1];
    const __bf16* Bc = Bs[kt & 1];
#pragma unroll
    for (int ks = 0; ks < 2; ++ks) {
      bf16x8 af[MI], bf[4];
      const int cb = ks * 4 + l16;
#pragma unroll
      for (int i = 0; i < MI; ++i) {
        const int rA = waveM * (TM / 2) + i * 16 + l15;
        af[i] = *(const bf16x8*)&Ac[rA * 64 + ((cb ^ (rA & 7)) * 8)];
      }
#pragma unroll
      for (int i = 0; i < 4; ++i) {
        const int rB = waveN * 64 + i * 16 + l15;
        bf[i] = *(const bf16x8*)&Bc[rB * 64 + ((cb ^ (rB & 7)) * 8)];
      }
#pragma unroll
      for (int mi = 0; mi < MI; ++mi)
#pragma unroll
        for (int ni = 0; ni < 4; ++ni)
          acc[mi][ni] = __builtin_amdgcn_mfma_f32_16x16x32_bf16(af[mi], bf[ni], acc[mi][ni], 0, 0, 0);
    }
  }

  if constexpr (MODE == 0) {
    const int which = n0 >> 9;          // block-uniform after W permutation
    const int b = m0 >> 11;
#pragma unroll
    for (int mi = 0; mi < MI; ++mi) {
#pragma unroll
      for (int ni = 0; ni < 4; ++ni) {
        const int n = n0 + waveN * 64 + ni * 16 + l15;
        const int d = n & 63, h = (n >> 6) & 7;
        const int t = (m0 & (T_ - 1)) + waveM * (TM / 2) + mi * 16 + l16 * 4;
        const size_t bh = (size_t)(b * H_ + h);
        if (which == 0) {
          bf16x4 pv;
#pragma unroll
          for (int r = 0; r < 4; ++r) pv[r] = (__bf16)(acc[mi][ni][r] * QSCALE);
          *(bf16x4*)&o0[(bh * D_ + d) * T_ + t] = pv;            // q [B,H,D,T]
        } else if (which == 1) {
#pragma unroll
          for (int r = 0; r < 4; ++r)
            o1[(bh * T_ + t + r) * D_ + d] = (__bf16)acc[mi][ni][r];  // k [B,H,T,D]
        } else {
          bf16x4 pv;
#pragma unroll
          for (int r = 0; r < 4; ++r) pv[r] = (__bf16)acc[mi][ni][r];
          *(bf16x4*)&o2[(bh * D_ + d) * T_ + t] = pv;            // v [B,H,D,T]
        }
      }
    }
  } else {
#pragma unroll
    for (int mi = 0; mi < MI; ++mi)
#pragma unroll
      for (int ni = 0; ni < 4; ++ni)
#pragma unroll
        for (int r = 0; r < 4; ++r) {
          const int m = m0 + waveM * (TM / 2) + mi * 16 + l16 * 4 + r;
          const int n = n0 + waveN * 64 + ni * 16 + l15;
          of[(size_t)m * N + n] = acc[mi][ni][r];
        }
  }
}

// Flash attention, max-free exp2-domain (R5 structure). Tk=64 double-buffered
// K/V staging, one barrier per kt. Waves 2x2 over (t-half 32, q-half 64).
// Ps is chunk-XOR swizzled (not padded): element P[q][t] lives at
//   q*32 + ((t>>3) ^ ((q>>1)&3))*8 + (t&7)
// -> both the bf16x4 writes and the b128 A-frag reads hit each bank group
//    exactly 2-way (lanes l15 and l15+8), which is free on gfx950 (m136).
__global__ __launch_bounds__(256, 2)
void attn_kernel(const __bf16* __restrict__ Q, const __bf16* __restrict__ Kk,
                 const __bf16* __restrict__ Vt, __bf16* __restrict__ Out) {
  __shared__ __align__(16) char smem[49152];
  // Ks[2]: 0, 8192 ([64 t][64 d] swizzled). Vts[2]: 16384, 24576 ([64 d][64 t]).
  // Ps: 32768, per-wave [64 q][32 t] chunk-swizzled bf16 (4096 B each).
  float* Osh = (float*)smem;               // overlay: [2 q2][64 d][68] f32
  float* Lsh = (float*)(smem + 34816);     // overlay: [2 q2][64 q'] f32

  const int tid = threadIdx.x, wave = tid >> 6, lane = tid & 63;
  const int l15 = lane & 15, l16 = lane >> 4;
  const int tw = wave >> 1, q2 = wave & 1;
  const int bh  = blockIdx.y;
  const int t0q = blockIdx.x * 128;
  const __bf16* qptr = Q  + (size_t)bh * D_ * T_;   // [D][T], pre-scaled
  const __bf16* kptr = Kk + (size_t)bh * T_ * D_;   // [T][D]
  const __bf16* vptr = Vt + (size_t)bh * D_ * T_;   // [D][T]

  __bf16* Pw = (__bf16*)(smem + 32768) + wave * 2048;   // [64 q][32 t] swizzled
  const int psw = (l15 >> 1) & 3;                       // per-lane chunk XOR key

  // Q fragments (wave's 64 q-cols), from [d][t]: one-time scalar loads.
  bf16x8 qf[4][2];
#pragma unroll
  for (int ni = 0; ni < 4; ++ni)
#pragma unroll
    for (int ks = 0; ks < 2; ++ks)
#pragma unroll
      for (int j = 0; j < 8; ++j)
        qf[ni][ks][j] = qptr[(size_t)(ks * 32 + l16 * 8 + j) * T_ +
                             t0q + q2 * 64 + ni * 16 + l15];

  bf16x8 ones;
#pragma unroll
  for (int j = 0; j < 8; ++j) ones[j] = (__bf16)1.0f;

  f32x4 oacc[4][4] = {};
  f32x4 lacc[4] = {};

  const int srow = lane >> 3;
  const int sch  = (lane & 7) ^ srow;

  auto stage = [&](int buf, int t0k) {
    __bf16* Kd = (__bf16*)(smem + buf * 8192);
    __bf16* Vd = (__bf16*)(smem + 16384 + buf * 8192);
#pragma unroll
    for (int i = 0; i < 2; ++i) {
      const int row = i * 32 + wave * 8;
      async_ld16(kptr + (size_t)(t0k + row + srow) * D_ + sch * 8, Kd + row * 64);
      async_ld16(vptr + (size_t)(row + srow) * T_ + t0k + sch * 8, Vd + row * 64);
    }
  };

  stage(0, 0);
#pragma unroll 2
  for (int kt = 0; kt < 32; ++kt) {
    __builtin_amdgcn_s_waitcnt(0);
    __syncthreads();
    if (kt < 31) stage((kt + 1) & 1, (kt + 1) * 64);
    const __bf16* Ksc = (const __bf16*)(smem + (kt & 1) * 8192);
    const __bf16* Vtc = (const __bf16*)(smem + 16384 + (kt & 1) * 8192);

    // S^T[t'][q'] over wave's 32 t x 64 q (log2 domain via QSCALE)
    f32x4 sacc[2][4] = {};
#pragma unroll
    for (int ks = 0; ks < 2; ++ks) {
      bf16x8 kf[2];
      const int cb = ks * 4 + l16;
#pragma unroll
      for (int mi = 0; mi < 2; ++mi) {
        const int rt = tw * 32 + mi * 16 + l15;
        kf[mi] = *(const bf16x8*)&Ksc[rt * 64 + ((cb ^ (rt & 7)) * 8)];
      }
#pragma unroll
      for (int mi = 0; mi < 2; ++mi)
#pragma unroll
        for (int ni = 0; ni < 4; ++ni)
          sacc[mi][ni] = __builtin_amdgcn_mfma_f32_16x16x32_bf16(kf[mi], qf[ni][ks], sacc[mi][ni], 0, 0, 0);
    }

    // P = exp2(S) -> wave-private Ps, chunk-swizzled.
    // t = mi*16 + l16*4 + r  ->  chunk = mi*2 + (l16>>1), intra = (l16&1)*4 + r
#pragma unroll
    for (int ni = 0; ni < 4; ++ni)
#pragma unroll
      for (int mi = 0; mi < 2; ++mi) {
        bf16x4 pv;
#pragma unroll
        for (int r = 0; r < 4; ++r) pv[r] = (__bf16)__builtin_amdgcn_exp2f(sacc[mi][ni][r]);
        *(bf16x4*)&Pw[(ni * 16 + l15) * 32 +
                      (((mi * 2 + (l16 >> 1)) ^ psw) * 8) + (l16 & 1) * 4] = pv;
      }

    // O += P*V over wave's 32 t ; l += P*1
    // A-frag read: t = l16*8 + j -> chunk = l16, intra = j
    {
      bf16x8 pf[4], vf[4];
#pragma unroll
      for (int mq = 0; mq < 4; ++mq)
        pf[mq] = *(const bf16x8*)&Pw[(mq * 16 + l15) * 32 + ((l16 ^ psw) * 8)];
#pragma unroll
      for (int nd = 0; nd < 4; ++nd) {
        const int rd = nd * 16 + l15;
        const int ct = tw * 4 + l16;
        vf[nd] = *(const bf16x8*)&Vtc[rd * 64 + ((ct ^ (rd & 7)) * 8)];
      }
#pragma unroll
      for (int mq = 0; mq < 4; ++mq) {
#pragma unroll
        for (int nd = 0; nd < 4; ++nd)
          oacc[mq][nd] = __builtin_amdgcn_mfma_f32_16x16x32_bf16(pf[mq], vf[nd], oacc[mq][nd], 0, 0, 0);
        lacc[mq] = __builtin_amdgcn_mfma_f32_16x16x32_bf16(pf[mq], ones, lacc[mq], 0, 0, 0);
      }
    }
  }

  // reduce O,l across t-halves; epilogue O/l -> [B,T,H*D] bf16
  __syncthreads();
  if (tw == 1) {
    float* Ow = Osh + q2 * 4352;            // [64 d][68] f32
#pragma unroll
    for (int mq = 0; mq < 4; ++mq)
#pragma unroll
      for (int nd = 0; nd < 4; ++nd)
        *(f32x4*)&Ow[(nd * 16 + l15) * 68 + mq * 16 + l16 * 4] = oacc[mq][nd];
    if (l15 == 0)
#pragma unroll
      for (int mq = 0; mq < 4; ++mq)
        *(f32x4*)&Lsh[q2 * 64 + mq * 16 + l16 * 4] = lacc[mq];
  }
  __syncthreads();
  if (tw == 0) {
    const int b = bh >> 3, hcol = (bh & 7) * D_;
    float* Ow = Osh + q2 * 4352;
#pragma unroll
    for (int mq = 0; mq < 4; ++mq) {
      const f32x4 lv = *(const f32x4*)&Lsh[q2 * 64 + mq * 16 + l16 * 4];
      f32x4 linv;
#pragma unroll
      for (int r = 0; r < 4; ++r) linv[r] = __builtin_amdgcn_rcpf(lacc[mq][r] + lv[r]);
#pragma unroll
      for (int nd = 0; nd < 4; ++nd) {
        const f32x4 op = *(const f32x4*)&Ow[(nd * 16 + l15) * 68 + mq * 16 + l16 * 4];
#pragma unroll
        for (int r = 0; r < 4; ++r) {
          const int trow = t0q + q2 * 64 + mq * 16 + l16 * 4 + r;
          Out[((size_t)b * T_ + trow) * E_ + hcol + nd * 16 + l15] =
              (__bf16)((oacc[mq][nd][r] + op[r]) * linv[r]);
        }
      }
    }
  }
}

extern "C" void kernel_launch(void* const* d_in, const int* in_sizes, int n_in,
                              void* d_out, int out_size, void* d_ws, size_t ws_size,
                              hipStream_t stream) {
  const float* x    = (const float*)d_in[0];
  const float* Wqkv = (const float*)d_in[1];
  const float* W0   = (const float*)d_in[2];
  float* out = (float*)d_out;

  char* ws = (char*)d_ws;
  __bf16* xb  = (__bf16*)ws;                                    // 8192*512 bf16
  __bf16* wqb = (__bf16*)(ws + 8388608);                        // 1536*512 (permuted)
  __bf16* w0b = (__bf16*)(ws + 8388608 + 1572864);              // 512*512
  __bf16* q   = (__bf16*)(ws + 8388608 + 1572864 + 524288);     // [B,H,D,T]
  __bf16* k   = q + 4194304;                                    // [B,H,T,D]
  __bf16* v   = k + 4194304;                                    // [B,H,D,T]
  __bf16* ao  = xb;  // reuse: xb consumed by QKV GEMM before attn writes ao

  cvt_all<<<2560, 256, 0, stream>>>(x, Wqkv, W0, xb, wqb, w0b);
  gemm_bt<0, 3 * H_ * D_, 128><<<dim3(12, 64), 256, 0, stream>>>(xb, wqb, q, k, v, nullptr);
  attn_kernel<<<dim3(16, 32), 256, 0, stream>>>(q, k, v, ao);
  gemm_bt<1, E_, 64><<<dim3(4, 128), 256, 0, stream>>>(ao, w0b, nullptr, nullptr, nullptr, out);
}